// Round 9
// baseline (178.861 us; speedup 1.0000x reference)
//
#include <hip/hip_runtime.h>
#include <hip/hip_bf16.h>
#include <stdint.h>

#define T_TOKENS 8192
#define D_DIM    1024
#define NE       10
#define NT       8
#define SEG      2048   // padded per-expert list capacity (actual ~1638+-40)

typedef unsigned short u16;
typedef __attribute__((ext_vector_type(8))) __bf16 bf16x8;
typedef __attribute__((ext_vector_type(4))) float  f32x4;
typedef __attribute__((ext_vector_type(8))) unsigned short u16x8;
typedef __attribute__((ext_vector_type(4))) unsigned short u16x4;

static __device__ __forceinline__ u16 f32_to_bf16(float f) {
  union { float f; uint32_t u; } v; v.f = f;
  uint32_t u = v.u;
  return (u16)((u + 0x7fffu + ((u >> 16) & 1u)) >> 16);
}
static __device__ __forceinline__ float bf16_to_f32(u16 u) {
  union { uint32_t u; float f; } v; v.u = ((uint32_t)u) << 16; return v.f;
}

// async 16B global->LDS DMA; LDS dest = wave-uniform base + lane*16 [m97/m104]
static __device__ __forceinline__ void async_load16(const u16* g, u16* l) {
  __builtin_amdgcn_global_load_lds(
      (const __attribute__((address_space(1))) void*)(const void*)g,
      (__attribute__((address_space(3))) void*)(void*)l, 16, 0, 0);
}

// ---------------------------------------------------------------------------
// Cross-round model: fixed harness overhead ~100us (measured R10); kernel
// time ~75us = gemm 45 + prep ~13 + combine ~14. gemm is the only lever.
// R11 (4-phase at BK=32) = null: clusters of 4 MFMA between barriers that
// still fired every 16 MFMA/wave — sync:work ratio unchanged. R12 is the
// pre-committed escalation: BK=64 + 2-buffer + 16-MFMA phases (m201/m248
// geometry) — 64 MFMA/wave per {2 barriers + 1 counted vmcnt}, 4x R9's
// amortization. m248v2 (grouped 256^2 K=1024, same op class): 8-phase
// full-stack = 1.29x over 2-phase; our 611 TF matches their 2ph 655.
// ---------------------------------------------------------------------------

// ---------------------------------------------------------------------------
// Kernel 1: prep = gate + weight-transpose fused (independent, BW-bound).
//   blockIdx.x <  1024 : gate role (8 tokens/block)
//   1024..3071         : transpose role (64x64 fp32->bf16 tile of W)
// ---------------------------------------------------------------------------
union PrepShared {
  struct { float gws[NE * D_DIM]; float gbs[NE]; int se[16]; float swt[16]; } g;
  struct { float tile[64][68]; } t;
};

__global__ __launch_bounds__(256) void prep_kernel(
    const float* __restrict__ x, const float* __restrict__ gw,
    const float* __restrict__ gb, const float* __restrict__ W,
    u16* __restrict__ xb, u16* __restrict__ wT,
    int* __restrict__ cnt, int* __restrict__ tokList,
    int* __restrict__ revIdx, float* __restrict__ revW) {
  __shared__ PrepShared sh;
  int tid = threadIdx.x;

  if (blockIdx.x >= 1024) {
    // ---- transpose role: W [e][d][j] fp32 -> wT [e][j][d] bf16 ----
    int tb = blockIdx.x - 1024;
    int e  = tb >> 8;
    int rem = tb & 255;
    int k0 = (rem >> 4) * 64;
    int n0 = (rem & 15) * 64;
    int cr = tid & 15;            // col-chunk (load) / k-chunk (store)
    int r0 = tid >> 4;            // 0..15
    const float* We = W + ((size_t)e << 20);
#pragma unroll
    for (int pass = 0; pass < 4; ++pass) {
      int r = pass * 16 + r0;     // k-row within tile
      f32x4 v = *(const f32x4*)&We[(size_t)(k0 + r) * 1024 + n0 + cr * 4];
#pragma unroll
      for (int j = 0; j < 4; ++j) sh.t.tile[cr * 4 + j][r] = v[j];
    }
    __syncthreads();
    u16* wTe = wT + ((size_t)e << 20);
#pragma unroll
    for (int pass = 0; pass < 4; ++pass) {
      int n = pass * 16 + r0;     // output row (n-dim)
      f32x4 tv = *(const f32x4*)&sh.t.tile[n][cr * 4];
      u16x4 pk;
#pragma unroll
      for (int j = 0; j < 4; ++j) pk[j] = f32_to_bf16(tv[j]);
      *(u16x4*)&wTe[(size_t)(n0 + n) * 1024 + k0 + cr * 4] = pk;
    }
    return;
  }

  // ---- gate role: 8 tokens/block ----
  {
    const f32x4* g4 = (const f32x4*)gw;
    f32x4* s4 = (f32x4*)sh.g.gws;
    for (int i = tid; i < NE * D_DIM / 4; i += 256) s4[i] = g4[i];
  }
  if (tid < NE) sh.g.gbs[tid] = gb[tid];
  __syncthreads();
  int lane = tid & 63;
  int wv   = tid >> 6;
  const f32x4* gws4 = (const f32x4*)sh.g.gws;
  for (int it = 0; it < 2; ++it) {
    int slot = wv * 2 + it;
    int t = blockIdx.x * 8 + slot;
    const f32x4* xr4 = (const f32x4*)(x + (size_t)t * D_DIM);
    f32x4 xv[4];
#pragma unroll
    for (int jj = 0; jj < 4; ++jj) xv[jj] = xr4[lane + 64 * jj];
    u16x4* xbr = (u16x4*)(xb + (size_t)t * D_DIM);
#pragma unroll
    for (int jj = 0; jj < 4; ++jj) {
      u16x4 pk;
#pragma unroll
      for (int k = 0; k < 4; ++k) pk[k] = f32_to_bf16(xv[jj][k]);
      xbr[lane + 64 * jj] = pk;
    }
    float logit[NE];
#pragma unroll
    for (int e = 0; e < NE; ++e) {
      float a = 0.f;
#pragma unroll
      for (int jj = 0; jj < 4; ++jj) {
        f32x4 gv = gws4[e * 256 + lane + 64 * jj];
#pragma unroll
        for (int k = 0; k < 4; ++k) a = fmaf(xv[jj][k], gv[k], a);
      }
#pragma unroll
      for (int off = 32; off >= 1; off >>= 1) a += __shfl_xor(a, off);
      logit[e] = a + sh.g.gbs[e];
    }
    float mx = logit[0];
#pragma unroll
    for (int e = 1; e < NE; ++e) mx = fmaxf(mx, logit[e]);
    float p[NE]; float s = 0.f;
#pragma unroll
    for (int e = 0; e < NE; ++e) { p[e] = expf(logit[e] - mx); s += p[e]; }
    int e0 = 0; float b0 = p[0];
#pragma unroll
    for (int e = 1; e < NE; ++e) if (p[e] > b0) { b0 = p[e]; e0 = e; }
    int e1 = -1; float b1 = -1.f;
#pragma unroll
    for (int e = 0; e < NE; ++e) if (e != e0 && p[e] > b1) { b1 = p[e]; e1 = e; }
    float w0 = b0 / s, w1 = b1 / s;
    float tw0 = (e0 < NT) ? w0 : 0.f;
    float tw1 = (e1 < NT) ? w1 : 0.f;
    float denom = tw0 + tw1;
    float nw0 = 0.f, nw1 = 0.f;
    if (denom > 0.f) { nw0 = tw0 / denom; nw1 = tw1 / denom; }
    if (lane == 0) {
      sh.g.se[slot * 2]     = (e0 < NT) ? e0 : -1;  sh.g.swt[slot * 2]     = nw0;
      sh.g.se[slot * 2 + 1] = (e1 < NT) ? e1 : -1;  sh.g.swt[slot * 2 + 1] = nw1;
      if (e0 >= NT) { revIdx[t * 2]     = -1; revW[t * 2]     = 0.f; }
      if (e1 >= NT) { revIdx[t * 2 + 1] = -1; revW[t * 2 + 1] = 0.f; }
    }
  }
  __syncthreads();
  // compaction: thread e<8 scans 16 (token,slot) entries; one padded atomic.
  if (tid < NT) {
    int e = tid, c = 0;
    for (int i = 0; i < 16; ++i) c += (sh.g.se[i] == e);
    if (c > 0) {
      int base = atomicAdd(&cnt[e * 32], c);
      int j = 0;
      for (int i = 0; i < 16; ++i) {
        if (sh.g.se[i] == e) {
          int tt  = blockIdx.x * 8 + (i >> 1);
          int pos = base + j;
          tokList[e * SEG + pos]   = tt;
          revIdx[tt * 2 + (i & 1)] = e * SEG + pos;
          revW[tt * 2 + (i & 1)]   = sh.g.swt[i];
          ++j;
        }
      }
    }
  }
}

// ---------------------------------------------------------------------------
// Kernel 2 (R12): per-expert gathered GEMM, m201-geometry.
// Tile 256x256, BK=64, 8 waves (2M x 4N; per-wave 128x64 out, acc 8x4).
// LDS: A/B double-buffered [2][256x64] bf16 = 128KB (+1KB tokS) -> 1
// block/CU. Grid (8 experts, 4 n-tiles, 8 m-tiles) = 256 blocks; expert =
// blockIdx.x -> XCD-affine (linear%8). K-loop 16 iters; per iter:
//   barrier                      (all waves done reading buf[cur^1])
//   issue 8 DMAs -> buf[cur^1]   (tile kt+1; A 4, B 4)
//   s_waitcnt vmcnt(8)           (tile kt's 8 landed; kt+1's stay in flight)
//   barrier                      (tile kt landed block-wide)
//   4 phases x { ds_read 4-8 frags; setprio(1); 16 MFMA; setprio(0); barrier }
// Phases = (ks, mt-half) quadrants; accumulate into same acc across ks/kt.
// Swizzle (XOR-8): global source chunk = (lane&7)^(lane>>3); read chunk
// p = (ks*4+q)^(lrow&7). Each ds_read_b128 wave64 touches every bank at
// exactly the 8-access floor -> conflict-free. Sources stay 128B-coalesced
// (permutation within each row's 128B window).
// Hazards: top barrier certifies reads of buf[cur^1] delivered (compiler
// lgkmcnt before each phase's MFMAs) before any wave re-targets it; second
// barrier certifies tile kt in LDS. All barriers block-uniform.
// Tail: rows >= c clamp to tokList[e*SEG]; garbage ybuf rows never read.
// ---------------------------------------------------------------------------
__global__ __launch_bounds__(512) void moe_gemm(
    const u16* __restrict__ xb, const u16* __restrict__ wT,
    const int* __restrict__ cnt, const int* __restrict__ tokList,
    const float* __restrict__ eb, u16* __restrict__ ybuf) {
  int e  = blockIdx.x;
  int c  = cnt[e * 32];
  int m0 = blockIdx.z * 256;
  if (m0 >= c) return;
  int n0 = blockIdx.y * 256;
  __shared__ __align__(16) u16 As[2][256 * 64];
  __shared__ __align__(16) u16 Bs[2][256 * 64];
  __shared__ int tokS[256];
  int tid = threadIdx.x;
  if (tid < 256) {
    int gm = m0 + tid;
    tokS[tid] = (gm < c) ? tokList[e * SEG + gm] : tokList[e * SEG];
  }
  __syncthreads();
  int lane = tid & 63;
  int wv   = tid >> 6;             // 0..7
  // ---- staging setup: wave wv covers rows [wv*32, +32) of A and of B ----
  int sub = lane >> 3;             // row-within-8, 0..7
  int chd = (lane & 7) ^ sub;      // global 16B chunk fetched (pre-swizzle)
  const u16* gA[4];
#pragma unroll
  for (int j = 0; j < 4; ++j) {
    int tok = tokS[wv * 32 + j * 8 + sub];
    gA[j] = xb + (size_t)tok * 1024 + chd * 8;
  }
  const u16* wTe = wT + ((size_t)e << 20);
  const u16* gB  = wTe + (size_t)(n0 + wv * 32 + sub) * 1024 + chd * 8;
  int ldsW = (wv * 32) * 64;       // wave's staging region (u16 offset)

  // ---- reader setup ----
  int wm = wv >> 2, wn = wv & 3;   // 2M x 4N; per-wave 128x64
  int lrow = lane & 15;
  int q    = lane >> 4;
  int pk0 = ((q)     ^ (lrow & 7)) * 8;   // ks=0: logical chunks 0..3
  int pk1 = ((4 + q) ^ (lrow & 7)) * 8;   // ks=1: logical chunks 4..7
  f32x4 acc[8][4];
#pragma unroll
  for (int i = 0; i < 8; ++i)
#pragma unroll
    for (int j = 0; j < 4; ++j) acc[i][j] = (f32x4){0.f, 0.f, 0.f, 0.f};

  // prologue: tile 0 -> buf 0 (8 loads in flight per wave)
#pragma unroll
  for (int j = 0; j < 4; ++j) {
    async_load16(gA[j], As[0] + ldsW + j * 512);
    async_load16(gB + j * 8192, Bs[0] + ldsW + j * 512);
  }

  int cur = 0;
  for (int kt = 0; kt < 16; ++kt) {
    // all waves done reading buf[cur^1] (kt-1's phase reads delivered
    // before their MFMAs via compiler lgkmcnt, which precede this barrier)
    asm volatile("s_barrier" ::: "memory");
    if (kt < 15) {
      int nx = cur ^ 1;
      int ko = (kt + 1) * 64;
#pragma unroll
      for (int j = 0; j < 4; ++j) {
        async_load16(gA[j] + ko, As[nx] + ldsW + j * 512);
        async_load16(gB + j * 8192 + ko, Bs[nx] + ldsW + j * 512);
      }
      // 16 outstanding (tiles kt, kt+1); retire tile kt's 8 only
      asm volatile("s_waitcnt vmcnt(8)" ::: "memory");
    } else {
      asm volatile("s_waitcnt vmcnt(0)" ::: "memory");
    }
    // tile kt landed block-wide
    asm volatile("s_barrier" ::: "memory");
    const u16* Ab = As[cur];
    const u16* Bb = Bs[cur];
    bf16x8 bfr[4], af[4];
    // ---- phase 0: ks=0, mt 0..3 ----
#pragma unroll
    for (int nt = 0; nt < 4; ++nt)
      bfr[nt] = *(const bf16x8*)(Bb + (wn * 64 + nt * 16 + lrow) * 64 + pk0);
#pragma unroll
    for (int mt = 0; mt < 4; ++mt)
      af[mt] = *(const bf16x8*)(Ab + (wm * 128 + mt * 16 + lrow) * 64 + pk0);
    __builtin_amdgcn_s_setprio(1);
#pragma unroll
    for (int mt = 0; mt < 4; ++mt)
#pragma unroll
      for (int nt = 0; nt < 4; ++nt)
        acc[mt][nt] = __builtin_amdgcn_mfma_f32_16x16x32_bf16(
            af[mt], bfr[nt], acc[mt][nt], 0, 0, 0);
    __builtin_amdgcn_s_setprio(0);
    asm volatile("s_barrier" ::: "memory");
    // ---- phase 1: ks=0, mt 4..7 ----
#pragma unroll
    for (int mt = 0; mt < 4; ++mt)
      af[mt] = *(const bf16x8*)(Ab + (wm * 128 + (mt + 4) * 16 + lrow) * 64 + pk0);
    __builtin_amdgcn_s_setprio(1);
#pragma unroll
    for (int mt = 0; mt < 4; ++mt)
#pragma unroll
      for (int nt = 0; nt < 4; ++nt)
        acc[mt + 4][nt] = __builtin_amdgcn_mfma_f32_16x16x32_bf16(
            af[mt], bfr[nt], acc[mt + 4][nt], 0, 0, 0);
    __builtin_amdgcn_s_setprio(0);
    asm volatile("s_barrier" ::: "memory");
    // ---- phase 2: ks=1, mt 0..3 ----
#pragma unroll
    for (int nt = 0; nt < 4; ++nt)
      bfr[nt] = *(const bf16x8*)(Bb + (wn * 64 + nt * 16 + lrow) * 64 + pk1);
#pragma unroll
    for (int mt = 0; mt < 4; ++mt)
      af[mt] = *(const bf16x8*)(Ab + (wm * 128 + mt * 16 + lrow) * 64 + pk1);
    __builtin_amdgcn_s_setprio(1);
#pragma unroll
    for (int mt = 0; mt < 4; ++mt)
#pragma unroll
      for (int nt = 0; nt < 4; ++nt)
        acc[mt][nt] = __builtin_amdgcn_mfma_f32_16x16x32_bf16(
            af[mt], bfr[nt], acc[mt][nt], 0, 0, 0);
    __builtin_amdgcn_s_setprio(0);
    asm volatile("s_barrier" ::: "memory");
    // ---- phase 3: ks=1, mt 4..7 (next iter's top barrier closes it) ----
#pragma unroll
    for (int mt = 0; mt < 4; ++mt)
      af[mt] = *(const bf16x8*)(Ab + (wm * 128 + (mt + 4) * 16 + lrow) * 64 + pk1);
    __builtin_amdgcn_s_setprio(1);
#pragma unroll
    for (int mt = 0; mt < 4; ++mt)
#pragma unroll
      for (int nt = 0; nt < 4; ++nt)
        acc[mt + 4][nt] = __builtin_amdgcn_mfma_f32_16x16x32_bf16(
            af[mt], bfr[nt], acc[mt + 4][nt], 0, 0, 0);
    __builtin_amdgcn_s_setprio(0);
    cur ^= 1;
  }
  // epilogue: C/D layout col=lane&15, row=(lane>>4)*4+reg [m89]
  int rq = lane >> 4;
  float bias[4];
#pragma unroll
  for (int nt = 0; nt < 4; ++nt)
    bias[nt] = eb[e * 1024 + n0 + wn * 64 + nt * 16 + lrow];
  u16* yb = ybuf + ((size_t)(e * SEG + m0)) * 1024 + n0 + wn * 64 + lrow;
#pragma unroll
  for (int mt = 0; mt < 8; ++mt) {
#pragma unroll
    for (int r = 0; r < 4; ++r) {
      int ml = wm * 128 + mt * 16 + rq * 4 + r;
      u16* row = yb + (size_t)ml * 1024;
#pragma unroll
      for (int nt = 0; nt < 4; ++nt)
        row[nt * 16] = f32_to_bf16(acc[mt][nt][r] + bias[nt]);
    }
  }
}

// ---------------------------------------------------------------------------
// Kernel 3: combine. out[t] = w0*ybuf[idx0] + w1*ybuf[idx1]  (pure BW).
// 2048 blocks x 4 tokens; ybuf reads cached; out write-once -> nt stores.
// ---------------------------------------------------------------------------
__global__ __launch_bounds__(256) void combine_kernel(
    const u16* __restrict__ ybuf, const int* __restrict__ revIdx,
    const float* __restrict__ revW, float* __restrict__ out) {
  int tid = threadIdx.x, lane = tid & 63, wv = tid >> 6;
  int t  = blockIdx.x * 4 + wv;
  int i0 = revIdx[t * 2], i1 = revIdx[t * 2 + 1];
  float w0 = revW[t * 2], w1 = revW[t * 2 + 1];
  float o[16];
#pragma unroll
  for (int k = 0; k < 16; ++k) o[k] = 0.f;
  if (i0 >= 0) {
    const u16x8* y = (const u16x8*)(ybuf + (size_t)i0 * 1024);
#pragma unroll
    for (int jj = 0; jj < 2; ++jj) {
      u16x8 v = y[lane + 64 * jj];
#pragma unroll
      for (int k = 0; k < 8; ++k) o[jj * 8 + k] += w0 * bf16_to_f32(v[k]);
    }
  }
  if (i1 >= 0) {
    const u16x8* y = (const u16x8*)(ybuf + (size_t)i1 * 1024);
#pragma unroll
    for (int jj = 0; jj < 2; ++jj) {
      u16x8 v = y[lane + 64 * jj];
#pragma unroll
      for (int k = 0; k < 8; ++k) o[jj * 8 + k] += w1 * bf16_to_f32(v[k]);
    }
  }
  f32x4* o4 = (f32x4*)(out + (size_t)t * 1024);
#pragma unroll
  for (int jj = 0; jj < 2; ++jj)
#pragma unroll
    for (int h = 0; h < 2; ++h) {
      f32x4 vv = {o[jj * 8 + h * 4], o[jj * 8 + h * 4 + 1],
                  o[jj * 8 + h * 4 + 2], o[jj * 8 + h * 4 + 3]};
      __builtin_nontemporal_store(vv, &o4[2 * (lane + 64 * jj) + h]);
    }
}

// ---------------------------------------------------------------------------
// Workspace layout (bytes), total ~64.2 MiB:
//   [0, 4096)        : int cnt[8*32] (one counter per 128B line)
//   [4096, +64K)     : tokList  8*2048 int (combined per-expert lists)
//   [+64K)           : revIdx   8192*2 int
//   [+64K)           : revW     8192*2 float
//   [+16M)           : xb   bf16 [8192][1024]
//   [+16M)           : wT   bf16 [8][1024][1024]
//   [+33.5M)         : ybuf bf16 [8*2048][1024]
// ---------------------------------------------------------------------------
extern "C" void kernel_launch(void* const* d_in, const int* in_sizes, int n_in,
                              void* d_out, int out_size, void* d_ws, size_t ws_size,
                              hipStream_t stream) {
  const float* x  = (const float*)d_in[0];
  const float* gw = (const float*)d_in[1];
  const float* gb = (const float*)d_in[2];
  const float* ew = (const float*)d_in[3];
  const float* eb = (const float*)d_in[4];
  float* out = (float*)d_out;
  char* ws = (char*)d_ws;
  int*   cnt     = (int*)ws;
  int*   tokList = (int*)(ws + 4096);
  int*   revIdx  = (int*)(ws + 4096 + 65536);
  float* revW    = (float*)(ws + 4096 + 131072);
  u16*   xb      = (u16*)(ws + 200704);
  u16*   wT      = (u16*)(ws + 200704 + 16777216);
  u16*   ybuf    = (u16*)(ws + 200704 + 33554432);

  hipMemsetAsync(cnt, 0, 4096, stream);
  prep_kernel<<<3072, 256, 0, stream>>>(x, gw, gb, ew, xb, wT, cnt, tokList,
                                        revIdx, revW);
  moe_gemm<<<dim3(8, 4, 8), 512, 0, stream>>>(xb, wT, cnt, tokList, eb, ybuf);
  combine_kernel<<<2048, 256, 0, stream>>>(ybuf, revIdx, revW, out);
}

// Round 11
// 173.761 us; speedup vs baseline: 1.0294x; 1.0294x over previous
//
#include <hip/hip_runtime.h>
#include <hip/hip_bf16.h>
#include <stdint.h>

#define T_TOKENS 8192
#define D_DIM    1024
#define NE       10
#define NT       8
#define SEG      2048   // padded per-expert list capacity (actual ~1638+-40)

typedef unsigned short u16;
typedef __attribute__((ext_vector_type(8))) __bf16 bf16x8;
typedef __attribute__((ext_vector_type(4))) float  f32x4;
typedef __attribute__((ext_vector_type(8))) unsigned short u16x8;
typedef __attribute__((ext_vector_type(4))) unsigned short u16x4;

static __device__ __forceinline__ u16 f32_to_bf16(float f) {
  union { float f; uint32_t u; } v; v.f = f;
  uint32_t u = v.u;
  return (u16)((u + 0x7fffu + ((u >> 16) & 1u)) >> 16);
}
static __device__ __forceinline__ float bf16_to_f32(u16 u) {
  union { uint32_t u; float f; } v; v.u = ((uint32_t)u) << 16; return v.f;
}

// async 16B global->LDS DMA; LDS dest = wave-uniform base + lane*16 [m97/m104]
static __device__ __forceinline__ void async_load16(const u16* g, u16* l) {
  __builtin_amdgcn_global_load_lds(
      (const __attribute__((address_space(1))) void*)(const void*)g,
      (__attribute__((address_space(3))) void*)(void*)l, 16, 0, 0);
}

// ---------------------------------------------------------------------------
// Cross-round model: fixed harness overhead ~100us (R10 cooperative probe);
// kernel time ~75us = gemm + prep ~16 + combine ~10. gemm is the lever.
// Ladder: R9 2-barrier BK=32 = 45.1; R11 4-phase BK=32 = null; R12 BK=64
// dbuf 4x16-MFMA phases = 42.8 (-5%). R13 = m201's fine interleave on the
// R12 geometry: ds_reads BEFORE each phase's barrier (latency hides under
// the barrier wait), G-loads spread 2/phase (m196: this interleave is the
// lever, -7..27% without), vmcnt folded at iter boundary with ~4 phases of
// slack. Pre-commit: gemm >= 41us -> practical structure ceiling, stop.
// (R10 bench was an infra flake — third "container failed twice"; R3/R7
// precedents both passed on identical resubmit. Kernel re-audited: barrier
// uniformity, dbuf both-direction hazards, LDS 129KB<160KB. Resubmit.)
// ---------------------------------------------------------------------------

// ---------------------------------------------------------------------------
// Kernel 1: prep = gate + weight-transpose fused (independent, BW-bound).
//   blockIdx.x <  1024 : gate role (8 tokens/block)
//   1024..3071         : transpose role (64x64 fp32->bf16 tile of W)
// ---------------------------------------------------------------------------
union PrepShared {
  struct { float gws[NE * D_DIM]; float gbs[NE]; int se[16]; float swt[16]; } g;
  struct { float tile[64][68]; } t;
};

__global__ __launch_bounds__(256) void prep_kernel(
    const float* __restrict__ x, const float* __restrict__ gw,
    const float* __restrict__ gb, const float* __restrict__ W,
    u16* __restrict__ xb, u16* __restrict__ wT,
    int* __restrict__ cnt, int* __restrict__ tokList,
    int* __restrict__ revIdx, float* __restrict__ revW) {
  __shared__ PrepShared sh;
  int tid = threadIdx.x;

  if (blockIdx.x >= 1024) {
    // ---- transpose role: W [e][d][j] fp32 -> wT [e][j][d] bf16 ----
    int tb = blockIdx.x - 1024;
    int e  = tb >> 8;
    int rem = tb & 255;
    int k0 = (rem >> 4) * 64;
    int n0 = (rem & 15) * 64;
    int cr = tid & 15;            // col-chunk (load) / k-chunk (store)
    int r0 = tid >> 4;            // 0..15
    const float* We = W + ((size_t)e << 20);
#pragma unroll
    for (int pass = 0; pass < 4; ++pass) {
      int r = pass * 16 + r0;     // k-row within tile
      f32x4 v = *(const f32x4*)&We[(size_t)(k0 + r) * 1024 + n0 + cr * 4];
#pragma unroll
      for (int j = 0; j < 4; ++j) sh.t.tile[cr * 4 + j][r] = v[j];
    }
    __syncthreads();
    u16* wTe = wT + ((size_t)e << 20);
#pragma unroll
    for (int pass = 0; pass < 4; ++pass) {
      int n = pass * 16 + r0;     // output row (n-dim)
      f32x4 tv = *(const f32x4*)&sh.t.tile[n][cr * 4];
      u16x4 pk;
#pragma unroll
      for (int j = 0; j < 4; ++j) pk[j] = f32_to_bf16(tv[j]);
      *(u16x4*)&wTe[(size_t)(n0 + n) * 1024 + k0 + cr * 4] = pk;
    }
    return;
  }

  // ---- gate role: 8 tokens/block ----
  {
    const f32x4* g4 = (const f32x4*)gw;
    f32x4* s4 = (f32x4*)sh.g.gws;
    for (int i = tid; i < NE * D_DIM / 4; i += 256) s4[i] = g4[i];
  }
  if (tid < NE) sh.g.gbs[tid] = gb[tid];
  __syncthreads();
  int lane = tid & 63;
  int wv   = tid >> 6;
  const f32x4* gws4 = (const f32x4*)sh.g.gws;
  for (int it = 0; it < 2; ++it) {
    int slot = wv * 2 + it;
    int t = blockIdx.x * 8 + slot;
    const f32x4* xr4 = (const f32x4*)(x + (size_t)t * D_DIM);
    f32x4 xv[4];
#pragma unroll
    for (int jj = 0; jj < 4; ++jj) xv[jj] = xr4[lane + 64 * jj];
    u16x4* xbr = (u16x4*)(xb + (size_t)t * D_DIM);
#pragma unroll
    for (int jj = 0; jj < 4; ++jj) {
      u16x4 pk;
#pragma unroll
      for (int k = 0; k < 4; ++k) pk[k] = f32_to_bf16(xv[jj][k]);
      xbr[lane + 64 * jj] = pk;
    }
    float logit[NE];
#pragma unroll
    for (int e = 0; e < NE; ++e) {
      float a = 0.f;
#pragma unroll
      for (int jj = 0; jj < 4; ++jj) {
        f32x4 gv = gws4[e * 256 + lane + 64 * jj];
#pragma unroll
        for (int k = 0; k < 4; ++k) a = fmaf(xv[jj][k], gv[k], a);
      }
#pragma unroll
      for (int off = 32; off >= 1; off >>= 1) a += __shfl_xor(a, off);
      logit[e] = a + sh.g.gbs[e];
    }
    float mx = logit[0];
#pragma unroll
    for (int e = 1; e < NE; ++e) mx = fmaxf(mx, logit[e]);
    float p[NE]; float s = 0.f;
#pragma unroll
    for (int e = 0; e < NE; ++e) { p[e] = expf(logit[e] - mx); s += p[e]; }
    int e0 = 0; float b0 = p[0];
#pragma unroll
    for (int e = 1; e < NE; ++e) if (p[e] > b0) { b0 = p[e]; e0 = e; }
    int e1 = -1; float b1 = -1.f;
#pragma unroll
    for (int e = 0; e < NE; ++e) if (e != e0 && p[e] > b1) { b1 = p[e]; e1 = e; }
    float w0 = b0 / s, w1 = b1 / s;
    float tw0 = (e0 < NT) ? w0 : 0.f;
    float tw1 = (e1 < NT) ? w1 : 0.f;
    float denom = tw0 + tw1;
    float nw0 = 0.f, nw1 = 0.f;
    if (denom > 0.f) { nw0 = tw0 / denom; nw1 = tw1 / denom; }
    if (lane == 0) {
      sh.g.se[slot * 2]     = (e0 < NT) ? e0 : -1;  sh.g.swt[slot * 2]     = nw0;
      sh.g.se[slot * 2 + 1] = (e1 < NT) ? e1 : -1;  sh.g.swt[slot * 2 + 1] = nw1;
      if (e0 >= NT) { revIdx[t * 2]     = -1; revW[t * 2]     = 0.f; }
      if (e1 >= NT) { revIdx[t * 2 + 1] = -1; revW[t * 2 + 1] = 0.f; }
    }
  }
  __syncthreads();
  // compaction: thread e<8 scans 16 (token,slot) entries; one padded atomic.
  if (tid < NT) {
    int e = tid, c = 0;
    for (int i = 0; i < 16; ++i) c += (sh.g.se[i] == e);
    if (c > 0) {
      int base = atomicAdd(&cnt[e * 32], c);
      int j = 0;
      for (int i = 0; i < 16; ++i) {
        if (sh.g.se[i] == e) {
          int tt  = blockIdx.x * 8 + (i >> 1);
          int pos = base + j;
          tokList[e * SEG + pos]   = tt;
          revIdx[tt * 2 + (i & 1)] = e * SEG + pos;
          revW[tt * 2 + (i & 1)]   = sh.g.swt[i];
          ++j;
        }
      }
    }
  }
}

// ---------------------------------------------------------------------------
// Kernel 2 (R13): per-expert gathered GEMM, R12 geometry + m201 interleave.
// Tile 256x256, BK=64, 8 waves (2M x 4N; per-wave 128x64, acc 8x4), LDS
// A/B dbuf [2][256x64] = 128KB -> 1 block/CU. Grid (8,4,8), expert =
// blockIdx.x (XCD-affine). K-loop 16 iters x 4 phases. Each phase
// (m201 template form):
//   ds_read THIS phase's 8 frags   (latency hides under the barrier wait)
//   issue 2 DMAs -> buf[nx]        (A pairs at ph0/1, B pairs at ph2/3)
//   s_barrier; lgkmcnt(0); setprio(1); 16 MFMA; setprio(0); s_barrier
// Iter boundary: vmcnt(0) before phase 3's closing barrier — oldest load
// has ~4 phases (>=800cy) in flight, so the wait retires cheaply (dbuf-
// compatible stand-in for the template's counted vmcnt(6)).
// Hazards: DMAs always target nx != cur; phase-3 reads delivered before
// its MFMAs (compiler lgkmcnt) which precede the boundary barrier, so next
// iter's DMAs into old-cur cannot race; all barriers block-uniform.
// Swizzle XOR-8 (R12, conflicts=0): stage chunk chd=(lane&7)^(lane>>3);
// read chunk (logical ^ (lrow&7)). Tail rows clamp to tokList[e*SEG].
// ---------------------------------------------------------------------------
__global__ __launch_bounds__(512) void moe_gemm(
    const u16* __restrict__ xb, const u16* __restrict__ wT,
    const int* __restrict__ cnt, const int* __restrict__ tokList,
    const float* __restrict__ eb, u16* __restrict__ ybuf) {
  int e  = blockIdx.x;
  int c  = cnt[e * 32];
  int m0 = blockIdx.z * 256;
  if (m0 >= c) return;
  int n0 = blockIdx.y * 256;
  __shared__ __align__(16) u16 As[2][256 * 64];
  __shared__ __align__(16) u16 Bs[2][256 * 64];
  __shared__ int tokS[256];
  int tid = threadIdx.x;
  if (tid < 256) {
    int gm = m0 + tid;
    tokS[tid] = (gm < c) ? tokList[e * SEG + gm] : tokList[e * SEG];
  }
  __syncthreads();
  int lane = tid & 63;
  int wv   = tid >> 6;             // 0..7
  // ---- staging setup: wave wv covers rows [wv*32, +32) of A and of B ----
  int sub = lane >> 3;             // row-within-8, 0..7
  int chd = (lane & 7) ^ sub;      // global 16B chunk fetched (pre-swizzle)
  const u16* gA[4];
#pragma unroll
  for (int j = 0; j < 4; ++j) {
    int tok = tokS[wv * 32 + j * 8 + sub];
    gA[j] = xb + (size_t)tok * 1024 + chd * 8;
  }
  const u16* wTe = wT + ((size_t)e << 20);
  const u16* gB  = wTe + (size_t)(n0 + wv * 32 + sub) * 1024 + chd * 8;
  int ldsW = (wv * 32) * 64;       // wave's staging region (u16 offset)

  // ---- reader setup ----
  int wm = wv >> 2, wn = wv & 3;   // 2M x 4N; per-wave 128x64
  int lrow = lane & 15;
  int q    = lane >> 4;
  int pk0 = ((q)     ^ (lrow & 7)) * 8;   // ks=0: logical chunks 0..3
  int pk1 = ((4 + q) ^ (lrow & 7)) * 8;   // ks=1: logical chunks 4..7
  f32x4 acc[8][4];
#pragma unroll
  for (int i = 0; i < 8; ++i)
#pragma unroll
    for (int j = 0; j < 4; ++j) acc[i][j] = (f32x4){0.f, 0.f, 0.f, 0.f};

  // prologue: tile 0 -> buf 0 (8 loads per wave), then drain + barrier
#pragma unroll
  for (int j = 0; j < 4; ++j) {
    async_load16(gA[j], As[0] + ldsW + j * 512);
    async_load16(gB + j * 8192, Bs[0] + ldsW + j * 512);
  }
  asm volatile("s_waitcnt vmcnt(0)" ::: "memory");
  asm volatile("s_barrier" ::: "memory");

  int cur = 0;
  for (int kt = 0; kt < 16; ++kt) {
    const u16* Ab = As[cur];
    const u16* Bb = Bs[cur];
    int nx = cur ^ 1;
    int ko = (kt + 1) * 64;
    int pf = (kt < 15);
    bf16x8 bfr[4], afl[4], afh[4];
    // ======== phase 0: ds_read B(ks0)+A-lo(ks0); DMA A pair 0 ========
#pragma unroll
    for (int nt = 0; nt < 4; ++nt)
      bfr[nt] = *(const bf16x8*)(Bb + (wn * 64 + nt * 16 + lrow) * 64 + pk0);
#pragma unroll
    for (int mt = 0; mt < 4; ++mt)
      afl[mt] = *(const bf16x8*)(Ab + (wm * 128 + mt * 16 + lrow) * 64 + pk0);
    if (pf) {
      async_load16(gA[0] + ko, As[nx] + ldsW);
      async_load16(gA[1] + ko, As[nx] + ldsW + 512);
    }
    asm volatile("s_barrier" ::: "memory");
    asm volatile("s_waitcnt lgkmcnt(0)" ::: "memory");
    __builtin_amdgcn_s_setprio(1);
#pragma unroll
    for (int mt = 0; mt < 4; ++mt)
#pragma unroll
      for (int nt = 0; nt < 4; ++nt)
        acc[mt][nt] = __builtin_amdgcn_mfma_f32_16x16x32_bf16(
            afl[mt], bfr[nt], acc[mt][nt], 0, 0, 0);
    __builtin_amdgcn_s_setprio(0);
    asm volatile("s_barrier" ::: "memory");
    // ======== phase 1: ds_read A-hi(ks0); DMA A pair 1 ========
#pragma unroll
    for (int mt = 0; mt < 4; ++mt)
      afh[mt] = *(const bf16x8*)(Ab + (wm * 128 + (mt + 4) * 16 + lrow) * 64 + pk0);
    if (pf) {
      async_load16(gA[2] + ko, As[nx] + ldsW + 1024);
      async_load16(gA[3] + ko, As[nx] + ldsW + 1536);
    }
    asm volatile("s_barrier" ::: "memory");
    asm volatile("s_waitcnt lgkmcnt(0)" ::: "memory");
    __builtin_amdgcn_s_setprio(1);
#pragma unroll
    for (int mt = 0; mt < 4; ++mt)
#pragma unroll
      for (int nt = 0; nt < 4; ++nt)
        acc[mt + 4][nt] = __builtin_amdgcn_mfma_f32_16x16x32_bf16(
            afh[mt], bfr[nt], acc[mt + 4][nt], 0, 0, 0);
    __builtin_amdgcn_s_setprio(0);
    asm volatile("s_barrier" ::: "memory");
    // ======== phase 2: ds_read B(ks1)+A-lo(ks1); DMA B pair 0 ========
#pragma unroll
    for (int nt = 0; nt < 4; ++nt)
      bfr[nt] = *(const bf16x8*)(Bb + (wn * 64 + nt * 16 + lrow) * 64 + pk1);
#pragma unroll
    for (int mt = 0; mt < 4; ++mt)
      afl[mt] = *(const bf16x8*)(Ab + (wm * 128 + mt * 16 + lrow) * 64 + pk1);
    if (pf) {
      async_load16(gB + ko, Bs[nx] + ldsW);
      async_load16(gB + 8192 + ko, Bs[nx] + ldsW + 512);
    }
    asm volatile("s_barrier" ::: "memory");
    asm volatile("s_waitcnt lgkmcnt(0)" ::: "memory");
    __builtin_amdgcn_s_setprio(1);
#pragma unroll
    for (int mt = 0; mt < 4; ++mt)
#pragma unroll
      for (int nt = 0; nt < 4; ++nt)
        acc[mt][nt] = __builtin_amdgcn_mfma_f32_16x16x32_bf16(
            afl[mt], bfr[nt], acc[mt][nt], 0, 0, 0);
    __builtin_amdgcn_s_setprio(0);
    asm volatile("s_barrier" ::: "memory");
    // ======== phase 3: ds_read A-hi(ks1); DMA B pair 1; boundary ========
#pragma unroll
    for (int mt = 0; mt < 4; ++mt)
      afh[mt] = *(const bf16x8*)(Ab + (wm * 128 + (mt + 4) * 16 + lrow) * 64 + pk1);
    if (pf) {
      async_load16(gB + 16384 + ko, Bs[nx] + ldsW + 1024);
      async_load16(gB + 24576 + ko, Bs[nx] + ldsW + 1536);
    }
    asm volatile("s_barrier" ::: "memory");
    asm volatile("s_waitcnt lgkmcnt(0)" ::: "memory");
    __builtin_amdgcn_s_setprio(1);
#pragma unroll
    for (int mt = 0; mt < 4; ++mt)
#pragma unroll
      for (int nt = 0; nt < 4; ++nt)
        acc[mt + 4][nt] = __builtin_amdgcn_mfma_f32_16x16x32_bf16(
            afh[mt], bfr[nt], acc[mt + 4][nt], 0, 0, 0);
    __builtin_amdgcn_s_setprio(0);
    // boundary: tile kt+1's 8 DMAs have ~4 phases in flight; retire them
    // before any wave's next phase-0 reads of buf[nx].
    asm volatile("s_waitcnt vmcnt(0)" ::: "memory");
    asm volatile("s_barrier" ::: "memory");
    cur ^= 1;
  }
  // epilogue: C/D layout col=lane&15, row=(lane>>4)*4+reg [m89]
  int rq = lane >> 4;
  float bias[4];
#pragma unroll
  for (int nt = 0; nt < 4; ++nt)
    bias[nt] = eb[e * 1024 + n0 + wn * 64 + nt * 16 + lrow];
  u16* yb = ybuf + ((size_t)(e * SEG + m0)) * 1024 + n0 + wn * 64 + lrow;
#pragma unroll
  for (int mt = 0; mt < 8; ++mt) {
#pragma unroll
    for (int r = 0; r < 4; ++r) {
      int ml = wm * 128 + mt * 16 + rq * 4 + r;
      u16* row = yb + (size_t)ml * 1024;
#pragma unroll
      for (int nt = 0; nt < 4; ++nt)
        row[nt * 16] = f32_to_bf16(acc[mt][nt][r] + bias[nt]);
    }
  }
}

// ---------------------------------------------------------------------------
// Kernel 3: combine. out[t] = w0*ybuf[idx0] + w1*ybuf[idx1]  (pure BW).
// 2048 blocks x 4 tokens; ybuf reads cached; out write-once -> nt stores.
// ---------------------------------------------------------------------------
__global__ __launch_bounds__(256) void combine_kernel(
    const u16* __restrict__ ybuf, const int* __restrict__ revIdx,
    const float* __restrict__ revW, float* __restrict__ out) {
  int tid = threadIdx.x, lane = tid & 63, wv = tid >> 6;
  int t  = blockIdx.x * 4 + wv;
  int i0 = revIdx[t * 2], i1 = revIdx[t * 2 + 1];
  float w0 = revW[t * 2], w1 = revW[t * 2 + 1];
  float o[16];
#pragma unroll
  for (int k = 0; k < 16; ++k) o[k] = 0.f;
  if (i0 >= 0) {
    const u16x8* y = (const u16x8*)(ybuf + (size_t)i0 * 1024);
#pragma unroll
    for (int jj = 0; jj < 2; ++jj) {
      u16x8 v = y[lane + 64 * jj];
#pragma unroll
      for (int k = 0; k < 8; ++k) o[jj * 8 + k] += w0 * bf16_to_f32(v[k]);
    }
  }
  if (i1 >= 0) {
    const u16x8* y = (const u16x8*)(ybuf + (size_t)i1 * 1024);
#pragma unroll
    for (int jj = 0; jj < 2; ++jj) {
      u16x8 v = y[lane + 64 * jj];
#pragma unroll
      for (int k = 0; k < 8; ++k) o[jj * 8 + k] += w1 * bf16_to_f32(v[k]);
    }
  }
  f32x4* o4 = (f32x4*)(out + (size_t)t * 1024);
#pragma unroll
  for (int jj = 0; jj < 2; ++jj)
#pragma unroll
    for (int h = 0; h < 2; ++h) {
      f32x4 vv = {o[jj * 8 + h * 4], o[jj * 8 + h * 4 + 1],
                  o[jj * 8 + h * 4 + 2], o[jj * 8 + h * 4 + 3]};
      __builtin_nontemporal_store(vv, &o4[2 * (lane + 64 * jj) + h]);
    }
}

// ---------------------------------------------------------------------------
// Workspace layout (bytes), total ~64.2 MiB:
//   [0, 4096)        : int cnt[8*32] (one counter per 128B line)
//   [4096, +64K)     : tokList  8*2048 int (combined per-expert lists)
//   [+64K)           : revIdx   8192*2 int
//   [+64K)           : revW     8192*2 float
//   [+16M)           : xb   bf16 [8192][1024]
//   [+16M)           : wT   bf16 [8][1024][1024]
//   [+33.5M)         : ybuf bf16 [8*2048][1024]
// ---------------------------------------------------------------------------
extern "C" void kernel_launch(void* const* d_in, const int* in_sizes, int n_in,
                              void* d_out, int out_size, void* d_ws, size_t ws_size,
                              hipStream_t stream) {
  const float* x  = (const float*)d_in[0];
  const float* gw = (const float*)d_in[1];
  const float* gb = (const float*)d_in[2];
  const float* ew = (const float*)d_in[3];
  const float* eb = (const float*)d_in[4];
  float* out = (float*)d_out;
  char* ws = (char*)d_ws;
  int*   cnt     = (int*)ws;
  int*   tokList = (int*)(ws + 4096);
  int*   revIdx  = (int*)(ws + 4096 + 65536);
  float* revW    = (float*)(ws + 4096 + 131072);
  u16*   xb      = (u16*)(ws + 200704);
  u16*   wT      = (u16*)(ws + 200704 + 16777216);
  u16*   ybuf    = (u16*)(ws + 200704 + 33554432);

  hipMemsetAsync(cnt, 0, 4096, stream);
  prep_kernel<<<3072, 256, 0, stream>>>(x, gw, gb, ew, xb, wT, cnt, tokList,
                                        revIdx, revW);
  moe_gemm<<<dim3(8, 4, 8), 512, 0, stream>>>(xb, wT, cnt, tokList, eb, ybuf);
  combine_kernel<<<2048, 256, 0, stream>>>(ybuf, revIdx, revW, out);
}